// Round 8
// baseline (362.957 us; speedup 1.0000x reference)
//
#include <hip/hip_runtime.h>
#include <math.h>

typedef _Float16 h16;
typedef __attribute__((ext_vector_type(4))) _Float16 half4;
typedef __attribute__((ext_vector_type(8))) _Float16 half8;
typedef __attribute__((ext_vector_type(4))) float f32x4;

#define AS1 __attribute__((address_space(1)))
#define AS3 __attribute__((address_space(3)))
#define MFMA16(a, b, c) __builtin_amdgcn_mfma_f32_16x16x32_f16((a), (b), (c), 0, 0, 0)

__device__ __forceinline__ float ex2(float x) {
  return __builtin_amdgcn_exp2f(x);
}

// ---------- convert: fp32 -> fp16 for q/k/v, Wq/Wk/Wv/Wo, rel ----------
__global__ __launch_bounds__(256) void convert(
    const float* __restrict__ q, const float* __restrict__ k,
    const float* __restrict__ v, const float* __restrict__ Wq,
    const float* __restrict__ Wk, const float* __restrict__ Wv,
    const float* __restrict__ Wo, const float* __restrict__ rel, h16* q16c,
    h16* k16c, h16* v16c, h16* Wq16, h16* Wk16, h16* Wv16, h16* Wo16,
    h16* relb) {
  const int i = blockIdx.x * 256 + threadIdx.x;  // float4 units
  if (i >= 4226304) return;
  const float* src;
  h16* dst;
  int off;
  if (i < 1048576) {
    src = q; dst = q16c; off = i;
  } else if (i < 2097152) {
    src = k; dst = k16c; off = i - 1048576;
  } else if (i < 3145728) {
    src = v; dst = v16c; off = i - 2097152;
  } else if (i < 3407872) {
    src = Wq; dst = Wq16; off = i - 3145728;
  } else if (i < 3670016) {
    src = Wk; dst = Wk16; off = i - 3407872;
  } else if (i < 3932160) {
    src = Wv; dst = Wv16; off = i - 3670016;
  } else if (i < 4194304) {
    src = Wo; dst = Wo16; off = i - 3932160;
  } else {
    off = i - 4194304;  // rel: 32000 f4 units; src valid below 31984
    half4 hv = (half4){(h16)0.f, (h16)0.f, (h16)0.f, (h16)0.f};
    if (off < 31984) {
      float4 f = *(const float4*)(rel + (size_t)off * 4);
      hv = (half4){(h16)f.x, (h16)f.y, (h16)f.z, (h16)f.w};
    }
    *(half4*)(relb + (size_t)off * 4) = hv;
    return;
  }
  float4 f = *(const float4*)(src + (size_t)off * 4);
  *(half4*)(dst + (size_t)off * 4) =
      (half4){(h16)f.x, (h16)f.y, (h16)f.z, (h16)f.w};
}

// ---------- 128x128 fp16 NT GEMM, global_load_lds staging ----------
// C[m,n] = sum_k A[m,k]*Bt[n,k] + bias[n]. M=4096,N=1024,K=1024.
// MODE 0: swapped operands (C rows = n) -> packed half4 out [B,H,T,64]
// MODE 1: normal (C rows = m)           -> packed half4 out [B,H,64,T]
template <int MODE>
__device__ __forceinline__ void gemm128_body(const h16* __restrict__ A,
                                             const h16* __restrict__ Bt,
                                             const float* __restrict__ bias,
                                             h16* __restrict__ outp) {
  __shared__ alignas(16) h16 As[128 * 32];
  __shared__ alignas(16) h16 Bs[128 * 32];
  const int tid = threadIdx.x;
  const int wave = tid >> 6;
  const int lane = tid & 63;
  const int wm = wave >> 1, wn = wave & 1;
  const int tm0 = blockIdx.x * 128, tn0 = blockIdx.y * 128;
  const int lrow = lane & 15;
  const int kq = lane >> 4;
  const int srow = lane >> 2;
  const int scol = (lane & 3) * 8;

  f32x4 acc[4][4];
#pragma unroll
  for (int i = 0; i < 4; ++i)
#pragma unroll
    for (int j = 0; j < 4; ++j) acc[i][j] = (f32x4){0.f, 0.f, 0.f, 0.f};

  for (int k0 = 0; k0 < 1024; k0 += 32) {
    __syncthreads();
#pragma unroll
    for (int rep = 0; rep < 2; ++rep) {
      const int cw = wave * 2 + rep;
      const int row = cw * 16 + srow;
      __builtin_amdgcn_global_load_lds(
          (const AS1 void*)(A + (size_t)(tm0 + row) * 1024 + k0 + scol),
          (AS3 void*)(As + cw * 512), 16, 0, 0);
      __builtin_amdgcn_global_load_lds(
          (const AS1 void*)(Bt + (size_t)(tn0 + row) * 1024 + k0 + scol),
          (AS3 void*)(Bs + cw * 512), 16, 0, 0);
    }
    __syncthreads();
    half8 af[4], bf[4];
#pragma unroll
    for (int i = 0; i < 4; ++i)
      af[i] = *(const half8*)(As + (wm * 64 + i * 16 + lrow) * 32 + kq * 8);
#pragma unroll
    for (int j = 0; j < 4; ++j)
      bf[j] = *(const half8*)(Bs + (wn * 64 + j * 16 + lrow) * 32 + kq * 8);
#pragma unroll
    for (int i = 0; i < 4; ++i)
#pragma unroll
      for (int j = 0; j < 4; ++j) {
        if (MODE == 0)
          acc[i][j] = MFMA16(bf[j], af[i], acc[i][j]);  // rows = n
        else
          acc[i][j] = MFMA16(af[i], bf[j], acc[i][j]);  // rows = m
      }
  }

  if (MODE == 0) {
    // row = n = tn0 + wn*64 + j*16 + kq*4 + r (r: d stride 1)
    // col = m = tm0 + wm*64 + i*16 + lrow
#pragma unroll
    for (int i = 0; i < 4; ++i) {
      const int m = tm0 + wm * 64 + i * 16 + lrow;
      const int b = m >> 10, t = m & 1023;
#pragma unroll
      for (int j = 0; j < 4; ++j) {
        const int n0 = tn0 + wn * 64 + j * 16 + kq * 4;
        const float4 bv = *(const float4*)(bias + n0);
        const int hh = n0 >> 6, d0 = n0 & 63;
        half4 hv = (half4){(h16)(acc[i][j][0] + bv.x), (h16)(acc[i][j][1] + bv.y),
                           (h16)(acc[i][j][2] + bv.z), (h16)(acc[i][j][3] + bv.w)};
        *(half4*)(outp + ((size_t)((b << 4) + hh) << 16) + (t << 6) + d0) = hv;
      }
    }
  } else {
    // row = m = tm0 + wm*64 + i*16 + kq*4 + r (r: t stride 1)
    // col = n = tn0 + wn*64 + j*16 + lrow
#pragma unroll
    for (int j = 0; j < 4; ++j) {
      const int n = tn0 + wn * 64 + j * 16 + lrow;
      const float bval = bias[n];
      const int hh = n >> 6, d = n & 63;
#pragma unroll
      for (int i = 0; i < 4; ++i) {
        const int m0 = tm0 + wm * 64 + i * 16 + kq * 4;
        const int b = m0 >> 10, t = m0 & 1023;
        half4 hv = (half4){(h16)(acc[i][j][0] + bval), (h16)(acc[i][j][1] + bval),
                           (h16)(acc[i][j][2] + bval), (h16)(acc[i][j][3] + bval)};
        *(half4*)(outp + (((size_t)((b << 4) + hh) * 64 + d) << 10) + t) = hv;
      }
    }
  }
}

__global__ __launch_bounds__(256) void qkv_gemm(
    const h16* q16c, const h16* k16c, const h16* v16c, const h16* Wq16,
    const h16* Wk16, const h16* Wv16, const float* bq, const float* bk,
    const float* bv, h16* q16, h16* k16, h16* vt16) {
  const int z = blockIdx.z;
  const h16* A = (z == 0) ? q16c : (z == 1) ? k16c : v16c;
  const h16* Bt = (z == 0) ? Wq16 : (z == 1) ? Wk16 : Wv16;
  const float* bias = (z == 0) ? bq : (z == 1) ? bk : bv;
  if (z == 2)
    gemm128_body<1>(A, Bt, bias, vt16);
  else
    gemm128_body<0>(A, Bt, bias, (z == 0) ? q16 : k16);
}

// ---------- out GEMM: 64x128 tile, fp32 out ----------
__global__ __launch_bounds__(256) void out_gemm(const h16* __restrict__ A,
                                                const h16* __restrict__ Bt,
                                                const float* __restrict__ bo,
                                                float* __restrict__ out) {
  __shared__ alignas(16) h16 As[64 * 32];
  __shared__ alignas(16) h16 Bs[128 * 32];
  const int tid = threadIdx.x;
  const int wave = tid >> 6;
  const int lane = tid & 63;
  const int wm = wave >> 1, wn = wave & 1;
  const int tm0 = blockIdx.x * 64, tn0 = blockIdx.y * 128;
  const int lrow = lane & 15;
  const int kq = lane >> 4;
  const int srow = lane >> 2;
  const int scol = (lane & 3) * 8;

  f32x4 acc[2][4];
#pragma unroll
  for (int i = 0; i < 2; ++i)
#pragma unroll
    for (int j = 0; j < 4; ++j) acc[i][j] = (f32x4){0.f, 0.f, 0.f, 0.f};

  for (int k0 = 0; k0 < 1024; k0 += 32) {
    __syncthreads();
    {
      const int row = wave * 16 + srow;
      __builtin_amdgcn_global_load_lds(
          (const AS1 void*)(A + (size_t)(tm0 + row) * 1024 + k0 + scol),
          (AS3 void*)(As + wave * 512), 16, 0, 0);
    }
#pragma unroll
    for (int rep = 0; rep < 2; ++rep) {
      const int cw = wave * 2 + rep;
      const int row = cw * 16 + srow;
      __builtin_amdgcn_global_load_lds(
          (const AS1 void*)(Bt + (size_t)(tn0 + row) * 1024 + k0 + scol),
          (AS3 void*)(Bs + cw * 512), 16, 0, 0);
    }
    __syncthreads();
    half8 af[2], bf[4];
#pragma unroll
    for (int i = 0; i < 2; ++i)
      af[i] = *(const half8*)(As + (wm * 32 + i * 16 + lrow) * 32 + kq * 8);
#pragma unroll
    for (int j = 0; j < 4; ++j)
      bf[j] = *(const half8*)(Bs + (wn * 64 + j * 16 + lrow) * 32 + kq * 8);
#pragma unroll
    for (int i = 0; i < 2; ++i)
#pragma unroll
      for (int j = 0; j < 4; ++j) acc[i][j] = MFMA16(af[i], bf[j], acc[i][j]);
  }

#pragma unroll
  for (int j = 0; j < 4; ++j) {
    const int n = tn0 + wn * 64 + j * 16 + lrow;
    const float bval = bo[n];
#pragma unroll
    for (int i = 0; i < 2; ++i) {
      const int rowb = wm * 32 + i * 16 + kq * 4;
#pragma unroll
      for (int r = 0; r < 4; ++r) {
        const int m = tm0 + rowb + r;
        out[(size_t)m * 1024 + n] = acc[i][j][r] + bval;
      }
    }
  }
}

// ---------- MFMA fused attention: barrier-free, direct-global fragments ----
// grid 1024; XCD swizzle: all 16 t-tiles of a bh land on one XCD (L2 reuse).
// Only LDS use: P C->A layout round-trip, own-wave rows only -> NO barriers.
__global__ __launch_bounds__(256, 4) void attn_mfma(
    const h16* __restrict__ q16, const h16* __restrict__ k16,
    const h16* __restrict__ vt16, const h16* __restrict__ q16c,
    const h16* __restrict__ relb, h16* __restrict__ ao) {
  __shared__ alignas(16) h16 Ps[4096];  // 8 KB [64][64] swizzled, per-wave rows

  const int i0 = blockIdx.x;
  const int bh = ((i0 & 7) << 3) | (i0 >> 7);   // xcd*8 + group
  const int ttile = (i0 >> 3) & 15;
  const int b = bh >> 4, h = bh & 15;
  const int t0 = ttile << 6;
  const int tid = threadIdx.x;
  const int w = tid >> 6;
  const int lane = tid & 63;
  const int l15 = lane & 15;
  const int kq = lane >> 4;

  // Q fragment (projected) + raw-Q fragment, reused across s-tiles
  const int tq = t0 + w * 16 + l15;
  half8 aq[2], arq[2];
#pragma unroll
  for (int ks = 0; ks < 2; ++ks) {
    aq[ks] =
        *(const half8*)(q16 + ((size_t)bh * 1024 + tq) * 64 + ks * 32 + kq * 8);
    arq[ks] = *(const half8*)(q16c + ((size_t)(b * 1024 + tq)) * 1024 + h * 64 +
                              ks * 32 + kq * 8);
  }

  float m2[4], ls[4];
  f32x4 O[4];
#pragma unroll
  for (int r = 0; r < 4; ++r) {
    m2[r] = -1e30f;
    ls[r] = 0.f;
  }
#pragma unroll
  for (int db = 0; db < 4; ++db) O[db] = (f32x4){0.f, 0.f, 0.f, 0.f};

  const int trow = w * 16 + kq * 4;
  const h16* kbh = k16 + ((size_t)bh << 10) * 64;
  const h16* vbh = vt16 + ((size_t)bh << 6) * 1024;

  for (int s0 = 0; s0 < 1024; s0 += 64) {
    // ---- QK^T strips: B-frags direct from global (L1/L2 resident) ----
    f32x4 S[4];
#pragma unroll
    for (int ns = 0; ns < 4; ++ns) {
      f32x4 s = (f32x4){0.f, 0.f, 0.f, 0.f};
      const int kr = s0 + ns * 16 + l15;
#pragma unroll
      for (int ks = 0; ks < 2; ++ks)
        s = MFMA16(aq[ks],
                   *(const half8*)(kbh + (size_t)kr * 64 + ks * 32 + kq * 8), s);
      S[ns] = s;
    }

    // ---- G[t][u] = rq . rel[u]; B-frags direct from relb ----
    const int base = s0 - t0 + 936;
    f32x4 G[5];
#pragma unroll
    for (int gi = 0; gi < 5; ++gi) {
      f32x4 g = (f32x4){0.f, 0.f, 0.f, 0.f};
      const int ur = (3 - w + gi) * 16 + l15;
      int ridx = base + ur;
      ridx = ridx < 0 ? 0 : (ridx > 1998 ? 1998 : ridx);
#pragma unroll
      for (int ks = 0; ks < 2; ++ks)
        g = MFMA16(arq[ks],
                   *(const half8*)(relb + (size_t)ridx * 64 + ks * 32 + kq * 8),
                   g);
      G[gi] = g;
    }

    // ---- in-register Toeplitz gather + logit scale ----
    const float SC = 11.54156032711170727f;  // 8 * log2(e)
    const int C0 = 63 - w * 16 - kq * 4;
#pragma unroll
    for (int ns = 0; ns < 4; ++ns) {
#pragma unroll
      for (int r = 0; r < 4; ++r) {
        const int u = l15 + C0 + ns * 16 - r;
        const int src = (kq << 4) | (u & 15);
        const int gsel = (u >> 4) + w - 3;  // in {ns, ns+1}
        const float v0 = __shfl(G[ns][r], src, 64);
        const float v1 = __shfl(G[(ns + 1) <= 4 ? (ns + 1) : 4][r], src, 64);
        const float g = (gsel == ns) ? v0 : v1;
        S[ns][r] = (S[ns][r] + g) * SC;
      }
    }

    // ---- online softmax (exp2 domain) + P write (own-wave rows) ----
#pragma unroll
    for (int r = 0; r < 4; ++r) {
      float mx = fmaxf(fmaxf(S[0][r], S[1][r]), fmaxf(S[2][r], S[3][r]));
      mx = fmaxf(mx, __shfl_xor(mx, 1));
      mx = fmaxf(mx, __shfl_xor(mx, 2));
      mx = fmaxf(mx, __shfl_xor(mx, 4));
      mx = fmaxf(mx, __shfl_xor(mx, 8));
      const float nm = fmaxf(m2[r], mx);
      const float al = ex2(m2[r] - nm);
      m2[r] = nm;
      const int t = trow + r;
      float rs = 0.f;
#pragma unroll
      for (int ns = 0; ns < 4; ++ns) {
        const float p = ex2(S[ns][r] - nm);
        rs += p;
        const int sl = ns * 16 + l15;
        Ps[t * 64 + (((sl >> 3) ^ (t & 7)) << 3) + (sl & 7)] = (h16)p;
      }
      rs += __shfl_xor(rs, 1);
      rs += __shfl_xor(rs, 2);
      rs += __shfl_xor(rs, 4);
      rs += __shfl_xor(rs, 8);
      ls[r] = ls[r] * al + rs;
      O[0][r] *= al;
      O[1][r] *= al;
      O[2][r] *= al;
      O[3][r] *= al;
    }

    // ---- PV: A = own-wave P rows (LDS), B = V^T rows direct global ----
    const int tp = w * 16 + l15;
#pragma unroll
    for (int ks = 0; ks < 2; ++ks) {
      const int ca = ((ks * 4 + kq) ^ (tp & 7)) << 3;
      half8 pa = *(const half8*)(Ps + tp * 64 + ca);
#pragma unroll
      for (int db = 0; db < 4; ++db) {
        const int vr = db * 16 + l15;
        O[db] = MFMA16(
            pa,
            *(const half8*)(vbh + (size_t)vr * 1024 + s0 + ks * 32 + kq * 8),
            O[db]);
      }
    }
  }

  // ---- epilogue -> ao fp16 [B*T, 1024] ----
#pragma unroll
  for (int r = 0; r < 4; ++r) {
    const float inv = 1.f / ls[r];
    const int t = t0 + trow + r;
    h16* op = ao + ((size_t)(b * 1024 + t)) * 1024 + h * 64;
#pragma unroll
    for (int db = 0; db < 4; ++db) op[db * 16 + l15] = (h16)(O[db][r] * inv);
  }
}

// ---------- launch ----------
extern "C" void kernel_launch(void* const* d_in, const int* in_sizes, int n_in,
                              void* d_out, int out_size, void* d_ws,
                              size_t ws_size, hipStream_t stream) {
  const float* query = (const float*)d_in[0];
  const float* key = (const float*)d_in[1];
  const float* value = (const float*)d_in[2];
  const float* Wq = (const float*)d_in[3];
  const float* bq = (const float*)d_in[4];
  const float* Wk = (const float*)d_in[5];
  const float* bk = (const float*)d_in[6];
  const float* Wv = (const float*)d_in[7];
  const float* bv = (const float*)d_in[8];
  const float* Wo = (const float*)d_in[9];
  const float* bo = (const float*)d_in[10];
  const float* rel = (const float*)d_in[11];

  char* ws = (char*)d_ws;
  h16* q16c = (h16*)ws;                          // 8 MB raw query fp16
  h16* k16c = (h16*)(ws + ((size_t)8 << 20));    // 8 MB raw key (ao aliases)
  h16* v16c = (h16*)(ws + ((size_t)16 << 20));   // 8 MB raw value
  h16* Wq16 = (h16*)(ws + ((size_t)24 << 20));   // 2 MB
  h16* Wk16 = (h16*)(ws + ((size_t)26 << 20));   // 2 MB
  h16* Wv16 = (h16*)(ws + ((size_t)28 << 20));   // 2 MB
  h16* Wo16 = (h16*)(ws + ((size_t)30 << 20));   // 2 MB
  h16* q16 = (h16*)(ws + ((size_t)32 << 20));    // 8 MB [B,H,T,64]
  h16* k16 = (h16*)(ws + ((size_t)40 << 20));    // 8 MB [B,H,T,64]
  h16* vt16 = (h16*)(ws + ((size_t)48 << 20));   // 8 MB [B,H,64,T]
  h16* relb = (h16*)(ws + ((size_t)56 << 20));   // 0.25 MB [2000,64]
  h16* ao = k16c;  // k16c dead after qkv_gemm
  float* out = (float*)d_out;

  convert<<<16509, 256, 0, stream>>>(query, key, value, Wq, Wk, Wv, Wo, rel,
                                     q16c, k16c, v16c, Wq16, Wk16, Wv16, Wo16,
                                     relb);
  qkv_gemm<<<dim3(32, 8, 3), 256, 0, stream>>>(q16c, k16c, v16c, Wq16, Wk16,
                                               Wv16, bq, bk, bv, q16, k16,
                                               vt16);
  attn_mfma<<<1024, 256, 0, stream>>>(q16, k16, vt16, q16c, relb, ao);
  out_gemm<<<dim3(64, 8), 256, 0, stream>>>(ao, Wo16, bo, out);
}